// Round 1
// baseline (1110.851 us; speedup 1.0000x reference)
//
#include <hip/hip_runtime.h>

#define N_PTS 262144
#define NG 128
#define GS 1024
#define FPS_B 16

typedef __attribute__((ext_vector_type(8))) short short8;
typedef __attribute__((ext_vector_type(8))) __bf16 bf16x8;
typedef __attribute__((ext_vector_type(4))) float f32x4;

__device__ __forceinline__ unsigned short f2bf(float f) {
  unsigned u = __float_as_uint(f);
  unsigned r = u + 0x7FFFu + ((u >> 16) & 1u);
  return (unsigned short)(r >> 16);
}

__device__ __forceinline__ f32x4 mfma16(short8 a, short8 b, f32x4 c) {
  return __builtin_amdgcn_mfma_f32_16x16x32_bf16(
      __builtin_bit_cast(bf16x8, a), __builtin_bit_cast(bf16x8, b), c, 0, 0, 0);
}

__device__ __forceinline__ unsigned long long shfl_xor_u64(unsigned long long v, int m) {
  unsigned lo = __shfl_xor((unsigned)v, m);
  unsigned hi = __shfl_xor((unsigned)(v >> 32), m);
  return ((unsigned long long)hi << 32) | lo;
}

__device__ __forceinline__ void gridbar(unsigned* cnt, unsigned target) {
  __syncthreads();
  if (threadIdx.x == 0) {
    __hip_atomic_fetch_add(cnt, 1u, __ATOMIC_ACQ_REL, __HIP_MEMORY_SCOPE_AGENT);
    while (__hip_atomic_load(cnt, __ATOMIC_ACQUIRE, __HIP_MEMORY_SCOPE_AGENT) < target)
      __builtin_amdgcn_s_sleep(2);
  }
  __syncthreads();
}

// ordered-uint encode for float (monotone for all finite floats)
__device__ __forceinline__ unsigned ordenc(float f) {
  unsigned u = __float_as_uint(f);
  return (u >> 31) ? ~u : (u | 0x80000000u);
}

__device__ __forceinline__ unsigned knn_key(float x, float y, float z, float pp,
                                            float sx, float sy, float sz, float s2) {
  float dot = __fmaf_rn(sx, x, __fmaf_rn(sy, y, __fmul_rn(sz, z)));
  float d2 = __fadd_rn(__fsub_rn(s2, __fadd_rn(dot, dot)), pp);
  return ordenc(d2);
}

// ---------------- prep: point norms + bf16 transposed weights ----------------
__global__ void __launch_bounds__(256) prep_kernel(const float* __restrict__ pc,
    const float* __restrict__ w2, const float* __restrict__ w3,
    float* __restrict__ p2, unsigned short* __restrict__ w2t,
    unsigned short* __restrict__ w3t) {
  int i = blockIdx.x * 256 + threadIdx.x;
  if (i < N_PTS) {
    float x = pc[i], y = pc[i + N_PTS], z = pc[i + 2 * N_PTS];
    p2[i] = __fadd_rn(__fadd_rn(__fmul_rn(x, x), __fmul_rn(y, y)), __fmul_rn(z, z));
  }
  if (i < 131072) { int n = i >> 7, k = i & 127; w3t[i] = f2bf(w3[k * 1024 + n]); }
  if (i < 8192)  { int n = i >> 6, k = i & 63;  w2t[i] = f2bf(w2[k * 128 + n]); }
}

// ---------------- FPS: persistent kernel, 1 grid barrier per selection -------
__global__ void __launch_bounds__(1024) fps_kernel(const float* __restrict__ pc,
    float* __restrict__ sampled_out, unsigned* __restrict__ bar,
    unsigned long long* __restrict__ partials, float* __restrict__ csum) {
  const int tid = threadIdx.x, bid = blockIdx.x;
  const int lane = tid & 63, wv = tid >> 6;
  const int gt = bid * 1024 + tid;
  const float* xs = pc;
  const float* ys = pc + N_PTS;
  const float* zs = pc + 2 * N_PTS;
  float x[16], y[16], z[16], md[16];
  float sx = 0.f, sy = 0.f, sz = 0.f;
#pragma unroll
  for (int j = 0; j < 16; ++j) {
    int i = gt + j * 16384;
    x[j] = xs[i]; y[j] = ys[i]; z[j] = zs[i];
    sx += x[j]; sy += y[j]; sz += z[j];
  }
#pragma unroll
  for (int m = 32; m; m >>= 1) {
    sx += __shfl_xor(sx, m); sy += __shfl_xor(sy, m); sz += __shfl_xor(sz, m);
  }
  __shared__ float rs[3][16];
  __shared__ unsigned long long wkey[16];
  __shared__ float bc[4];
  if (lane == 0) { rs[0][wv] = sx; rs[1][wv] = sy; rs[2][wv] = sz; }
  __syncthreads();
  unsigned phase = 0;
  if (tid == 0) {
    float ax = 0.f, ay = 0.f, az = 0.f;
    for (int w = 0; w < 16; ++w) { ax += rs[0][w]; ay += rs[1][w]; az += rs[2][w]; }
    __hip_atomic_store(&csum[bid * 4 + 0], ax, __ATOMIC_RELAXED, __HIP_MEMORY_SCOPE_AGENT);
    __hip_atomic_store(&csum[bid * 4 + 1], ay, __ATOMIC_RELAXED, __HIP_MEMORY_SCOPE_AGENT);
    __hip_atomic_store(&csum[bid * 4 + 2], az, __ATOMIC_RELAXED, __HIP_MEMORY_SCOPE_AGENT);
  }
  gridbar(bar, (++phase) * FPS_B);
  if (tid == 0) {
    float ax = 0.f, ay = 0.f, az = 0.f;
    for (int w = 0; w < FPS_B; ++w) {
      ax += __hip_atomic_load(&csum[w * 4 + 0], __ATOMIC_RELAXED, __HIP_MEMORY_SCOPE_AGENT);
      ay += __hip_atomic_load(&csum[w * 4 + 1], __ATOMIC_RELAXED, __HIP_MEMORY_SCOPE_AGENT);
      az += __hip_atomic_load(&csum[w * 4 + 2], __ATOMIC_RELAXED, __HIP_MEMORY_SCOPE_AGENT);
    }
    bc[1] = ax * (1.f / N_PTS); bc[2] = ay * (1.f / N_PTS); bc[3] = az * (1.f / N_PTS);
  }
  __syncthreads();
  {
    float cx = bc[1], cy = bc[2], cz = bc[3];
#pragma unroll
    for (int j = 0; j < 16; ++j) {
      float dx = x[j] - cx, dy = y[j] - cy, dz = z[j] - cz;
      md[j] = sqrtf(dx * dx + dy * dy + dz * dz);
    }
  }
  for (int sel = 0; sel < NG; ++sel) {
    unsigned long long key = 0ull;
#pragma unroll
    for (int j = 0; j < 16; ++j) {
      unsigned fb = __float_as_uint(md[j]);
      unsigned long long k =
          ((unsigned long long)fb << 32) | (unsigned)(~(gt + j * 16384));
      if (k > key) key = k;
    }
#pragma unroll
    for (int m = 32; m; m >>= 1) {
      unsigned long long o = shfl_xor_u64(key, m);
      if (o > key) key = o;
    }
    if (lane == 0) wkey[wv] = key;
    __syncthreads();
    if (tid == 0) {
      unsigned long long bk = 0ull;
      for (int w = 0; w < 16; ++w) if (wkey[w] > bk) bk = wkey[w];
      __hip_atomic_store(&partials[(sel & 1) * FPS_B + bid], bk, __ATOMIC_RELEASE,
                         __HIP_MEMORY_SCOPE_AGENT);
    }
    gridbar(bar, (++phase) * FPS_B);
    if (tid == 0) {
      unsigned long long bk = 0ull;
      for (int w = 0; w < FPS_B; ++w) {
        unsigned long long v = __hip_atomic_load(&partials[(sel & 1) * FPS_B + w],
                                                 __ATOMIC_RELAXED, __HIP_MEMORY_SCOPE_AGENT);
        if (v > bk) bk = v;
      }
      unsigned wi = ~(unsigned)(bk & 0xFFFFFFFFull);
      float wx = xs[wi], wy = ys[wi], wz = zs[wi];
      bc[1] = wx; bc[2] = wy; bc[3] = wz;
      if (bid == 0) {
        sampled_out[sel * 3 + 0] = wx;
        sampled_out[sel * 3 + 1] = wy;
        sampled_out[sel * 3 + 2] = wz;
      }
    }
    __syncthreads();
    {
      float wx = bc[1], wy = bc[2], wz = bc[3];
#pragma unroll
      for (int j = 0; j < 16; ++j) {
        float dx = x[j] - wx, dy = y[j] - wy, dz = z[j] - wz;
        float d = sqrtf(dx * dx + dy * dy + dz * dz);
        md[j] = (sel == 0) ? d : fminf(md[j], d);
      }
    }
  }
}

// ---------------- KNN: exact 1024-smallest via 3-level radix histogram -------
__global__ void __launch_bounds__(1024) knn_kernel(const float* __restrict__ pc,
    const float* __restrict__ p2, const float* __restrict__ sampled,
    int* __restrict__ knn) {
  const int g = blockIdx.x;
  const int tid = threadIdx.x;
  const int lane = tid & 63;
  __shared__ unsigned hist[2048];
  __shared__ unsigned sres[2];
  __shared__ unsigned scnt[2];
  __shared__ int ebuf[1024];
  const float* xs = pc;
  const float* ys = pc + N_PTS;
  const float* zs = pc + 2 * N_PTS;
  const float sx = sampled[g * 3 + 0], sy = sampled[g * 3 + 1], sz = sampled[g * 3 + 2];
  const float s2 = __fadd_rn(__fadd_rn(__fmul_rn(sx, sx), __fmul_rn(sy, sy)),
                             __fmul_rn(sz, sz));
  unsigned prefix = 0, krem = GS;
  const int shs[3] = {21, 10, 0};
  const int nbs[3] = {11, 11, 10};
  for (int lvl = 0; lvl < 3; ++lvl) {
    const int sh = shs[lvl], nb = nbs[lvl];
    const unsigned hs = (lvl == 0) ? 0u : (unsigned)(sh + nb);
    const unsigned msk = (1u << nb) - 1u;
    for (int i = tid; i < 2048; i += 1024) hist[i] = 0u;
    __syncthreads();
    for (int i = tid; i < N_PTS; i += 1024) {
      unsigned k = knn_key(xs[i], ys[i], zs[i], p2[i], sx, sy, sz, s2);
      bool act = (lvl == 0) || ((k >> hs) == prefix);
      if (act) atomicAdd(&hist[(k >> sh) & msk], 1u);
    }
    __syncthreads();
    const int per = (int)((msk + 1u) >> 6);
    if (tid < 64) {
      unsigned local = 0;
      for (int j = 0; j < per; ++j) local += hist[lane * per + j];
      unsigned inc = local;
      for (int off = 1; off < 64; off <<= 1) {
        unsigned v = __shfl_up(inc, off);
        if (lane >= off) inc += v;
      }
      unsigned exc = inc - local;
      if (exc < krem && krem <= inc) {
        unsigned c = exc;
        for (int j = 0; j < per; ++j) {
          unsigned h = hist[lane * per + j];
          if (c + h >= krem) { sres[0] = (unsigned)(lane * per + j); sres[1] = c; break; }
          c += h;
        }
      }
    }
    __syncthreads();
    prefix = (prefix << nb) | sres[0];
    krem -= sres[1];
    __syncthreads();
  }
  const unsigned T = prefix;
  if (tid == 0) { scnt[0] = 0u; scnt[1] = 0u; }
  __syncthreads();
  for (int i = tid; i < N_PTS; i += 1024) {
    unsigned k = knn_key(xs[i], ys[i], zs[i], p2[i], sx, sy, sz, s2);
    if (k < T) {
      unsigned pos = atomicAdd(&scnt[0], 1u);
      knn[g * GS + pos] = i;
    } else if (k == T) {
      unsigned e = atomicAdd(&scnt[1], 1u);
      if (e < 1024u) ebuf[e] = i;
    }
  }
  __syncthreads();
  if (tid < 64) {
    int ec = (int)min(scnt[1], 1024u);
    int base = (int)scnt[0];
    for (int j = 0; j < (int)krem; ++j) {
      int best = 0x7FFFFFFF;
      for (int p = lane; p < ec; p += 64) best = min(best, ebuf[p]);
      for (int m = 32; m; m >>= 1) best = min(best, __shfl_xor(best, m));
      for (int p = lane; p < ec; p += 64)
        if (ebuf[p] == best) ebuf[p] = 0x7FFFFFFF;
      if (lane == 0) knn[g * GS + base + j] = best;
    }
  }
}

// ---------------- fused MLP (3->64->128->1024) + max-pool, bf16 MFMA ---------
__global__ void __launch_bounds__(256, 2) mlp_kernel(const float* __restrict__ pc,
    const int* __restrict__ knn, const float* __restrict__ w1,
    const unsigned short* __restrict__ w2t, const unsigned short* __restrict__ w3t,
    unsigned* __restrict__ gout) {
  const int blk = blockIdx.x, g = blk >> 2, split = blk & 3;
  const int tid = threadIdx.x, lane = tid & 63, wv = tid >> 6;
  __shared__ unsigned gmax[1024];
  __shared__ __align__(16) short h1[128 * 72];
  __shared__ __align__(16) short h2[128 * 136];
  __shared__ float cxs[128], cys[128], czs[128];
  for (int i = tid; i < 1024; i += 256) gmax[i] = 0u;
  const float* xs = pc;
  const float* ys = pc + N_PTS;
  const float* zs = pc + 2 * N_PTS;
  const int ch = tid & 63;
  const int pgrp = tid >> 6;
  const float w10 = w1[ch], w11 = w1[64 + ch], w12 = w1[128 + ch];
  const int r0 = (lane >> 4) * 4;
  const int cB = lane & 15;
  const int kB = (lane >> 4) * 8;
  for (int tile = 0; tile < 2; ++tile) {
    __syncthreads();
    if (tid < 128) {
      int i = knn[g * 1024 + split * 256 + tile * 128 + tid];
      cxs[tid] = xs[i]; cys[tid] = ys[i]; czs[tid] = zs[i];
    }
    __syncthreads();
    // H1 = relu(X @ w1) -> LDS bf16 [128][72]
    for (int q = 0; q < 32; ++q) {
      int p = pgrp * 32 + q;
      float v = fmaxf(__fmaf_rn(cxs[p], w10, __fmaf_rn(cys[p], w11, czs[p] * w12)), 0.f);
      h1[p * 72 + ch] = (short)f2bf(v);
    }
    __syncthreads();
    // H2 = relu(H1 @ w2) -> LDS bf16 [128][136]
    {
      short8 a[2][2];
#pragma unroll
      for (int mt = 0; mt < 2; ++mt)
#pragma unroll
        for (int ks = 0; ks < 2; ++ks)
          a[mt][ks] = *(const short8*)&h1[((2 * wv + mt) * 16 + cB) * 72 + kB + ks * 32];
#pragma unroll
      for (int n0 = 0; n0 < 8; ++n0) {
        short8 bb[2];
#pragma unroll
        for (int ks = 0; ks < 2; ++ks)
          bb[ks] = *(const short8*)&w2t[(n0 * 16 + cB) * 64 + kB + ks * 32];
#pragma unroll
        for (int mt = 0; mt < 2; ++mt) {
          f32x4 acc = {0.f, 0.f, 0.f, 0.f};
          acc = mfma16(a[mt][0], bb[0], acc);
          acc = mfma16(a[mt][1], bb[1], acc);
          int rr = (2 * wv + mt) * 16 + r0;
#pragma unroll
          for (int r = 0; r < 4; ++r)
            h2[(rr + r) * 136 + n0 * 16 + cB] = (short)f2bf(fmaxf(acc[r], 0.f));
        }
      }
    }
    __syncthreads();
    // H3 = H2 @ w3 ; max over points -> gmax
    {
      short8 a2[2][4];
#pragma unroll
      for (int mt = 0; mt < 2; ++mt)
#pragma unroll
        for (int ks = 0; ks < 4; ++ks)
          a2[mt][ks] = *(const short8*)&h2[((2 * wv + mt) * 16 + cB) * 136 + kB + ks * 32];
      for (int n0 = 0; n0 < 64; ++n0) {
        short8 b3[4];
#pragma unroll
        for (int ks = 0; ks < 4; ++ks)
          b3[ks] = *(const short8*)&w3t[(n0 * 16 + cB) * 128 + kB + ks * 32];
        f32x4 acc0 = {0.f, 0.f, 0.f, 0.f}, acc1 = {0.f, 0.f, 0.f, 0.f};
#pragma unroll
        for (int ks = 0; ks < 4; ++ks) acc0 = mfma16(a2[0][ks], b3[ks], acc0);
#pragma unroll
        for (int ks = 0; ks < 4; ++ks) acc1 = mfma16(a2[1][ks], b3[ks], acc1);
        float mv = fmaxf(fmaxf(fmaxf(acc0[0], acc0[1]), fmaxf(acc0[2], acc0[3])),
                         fmaxf(fmaxf(acc1[0], acc1[1]), fmaxf(acc1[2], acc1[3])));
        mv = fmaxf(mv, __shfl_xor(mv, 16));
        mv = fmaxf(mv, __shfl_xor(mv, 32));
        if (lane < 16) atomicMax(&gmax[n0 * 16 + lane], ordenc(mv));
      }
    }
  }
  __syncthreads();
  for (int i = tid; i < 1024; i += 256)
    gout[(g * 4 + split) * 1024 + i] = gmax[i];
}

// ---------------- combine split partials -> d_out ----------------------------
__global__ void __launch_bounds__(256) combine_kernel(const unsigned* __restrict__ gm,
                                                      float* __restrict__ out) {
  int c = blockIdx.x * 256 + threadIdx.x;
  int g = c >> 10, chn = c & 1023;
  unsigned m = 0u;
#pragma unroll
  for (int s = 0; s < 4; ++s) {
    unsigned v = gm[(g * 4 + s) * 1024 + chn];
    if (v > m) m = v;
  }
  out[c] = (m >> 31) ? __uint_as_float(m ^ 0x80000000u) : __uint_as_float(~m);
}

extern "C" void kernel_launch(void* const* d_in, const int* in_sizes, int n_in,
                              void* d_out, int out_size, void* d_ws, size_t ws_size,
                              hipStream_t stream) {
  (void)in_sizes; (void)n_in; (void)out_size; (void)ws_size;
  const float* pc = (const float*)d_in[0];
  const float* w1 = (const float*)d_in[1];
  const float* w2 = (const float*)d_in[2];
  const float* w3 = (const float*)d_in[3];
  float* out = (float*)d_out;
  char* ws = (char*)d_ws;

  unsigned* bar = (unsigned*)(ws + 0);                          // 64 B
  unsigned long long* partials = (unsigned long long*)(ws + 256); // 256 B
  float* csum = (float*)(ws + 512);                             // 256 B
  float* p2 = (float*)(ws + 1024);                              // 1 MiB
  unsigned short* w2t = (unsigned short*)(ws + 1024 + 1048576);           // 16 KiB
  unsigned short* w3t = (unsigned short*)(ws + 1024 + 1048576 + 16384);   // 256 KiB
  int* knn = (int*)(ws + 1024 + 1048576 + 16384 + 262144);                // 512 KiB
  unsigned* gout = (unsigned*)(ws + 1024 + 1048576 + 16384 + 262144 + 524288); // 2 MiB
  float* sampled = out + 131072;

  hipMemsetAsync(bar, 0, 64, stream);
  prep_kernel<<<1024, 256, 0, stream>>>(pc, w2, w3, p2, w2t, w3t);
  fps_kernel<<<FPS_B, 1024, 0, stream>>>(pc, sampled, bar, partials, csum);
  knn_kernel<<<NG, 1024, 0, stream>>>(pc, p2, sampled, knn);
  mlp_kernel<<<NG * 4, 256, 0, stream>>>(pc, knn, w1, w2t, w3t, gout);
  combine_kernel<<<512, 256, 0, stream>>>(gout, out);
}